// Round 2
// baseline (853.974 us; speedup 1.0000x reference)
//
#include <hip/hip_runtime.h>
#include <stdint.h>

// ---------------------------------------------------------------------------
// Lingunet5Filter: 5x dynamic 1x1 conv (per-sample weight) + instance norm
// on levels 1-4.  Per (b, level): Y[o,s] = sum_c F[b,o,c] * X[b,c,s], then
// (Y - mean_s Y) * rsqrt(var_s Y + 1e-5) for levels 1-4.
//
// Round 2 design (resubmitted after infra failure in round 1):
//  - conv: 128(o) x 128(s) x K=128(c) tile per block, 4 waves (2x2), bf16
//    MFMA 16x16x32, fp32 accum.
//  - X is staged TRANSPOSED into LDS (Xt[s][c], c contiguous) via a 4x4
//    register transpose, so BOTH A and B fragments are single ds_read_b128
//    (the old per-element ds_read_u16 gather was the latency killer).
//  - XOR swizzle on 16B slots: slot ^= (row&7)^((row>>3)&7).  b128 reads
//    2-way (free), b64 staging writes at the 4-pass hardware floor.
//  - Blocks loop over several s-tiles (nblk per sample): F staged once per
//    block; next tile's global loads issued right after the staging barrier
//    so HBM stays busy under MFMA + epilogue.
//  - fp32->bf16 via (__bf16) casts -> v_cvt_pk_bf16_f32 (RNE), not the
//    4-op software round.
//  - stats (Sum y, Sum y^2) per (b,o) via wave reduce + global atomics; y
//    stored bf16 to workspace; norm kernel rescales to fp32 out.
// ---------------------------------------------------------------------------

typedef __bf16 bf16;
typedef __bf16 bf16x8 __attribute__((ext_vector_type(8)));
typedef float f32x4 __attribute__((ext_vector_type(4)));
typedef unsigned short u16;
typedef u16 u16x4 __attribute__((ext_vector_type(4)));
typedef u16 u16x8 __attribute__((ext_vector_type(8)));

__device__ __forceinline__ float bf2f(u16 h) {
    return __builtin_bit_cast(float, (uint32_t)h << 16);
}
__device__ __forceinline__ u16x4 cvt4(f32x4 v) {
    u16x4 r;
#pragma unroll
    for (int i = 0; i < 4; ++i) {
        bf16 h = (bf16)v[i];                 // HW cvt, RNE
        r[i] = __builtin_bit_cast(u16, h);
    }
    return r;
}
// 16B-slot XOR swizzle, in u16-element units (toggles element bits 3..5).
// For 16 consecutive rows it is a permutation mod 8 -> 2-way reads (free);
// for the 4-rows-apart staging writes it spreads 8 slots -> 4-pass floor.
__device__ __forceinline__ int swz8(int r) {
    return ((r & 7) ^ ((r >> 3) & 7)) << 3;
}

template<bool YBF16>
__global__ __launch_bounds__(256, 2)
void conv_kernel(const float* __restrict__ x, const float* __restrict__ fw,
                 float* __restrict__ out, u16* __restrict__ ybf,
                 float* __restrict__ ysum, float* __restrict__ ysq,
                 int HW, int ntiles, int nblk, int do_stats)
{
    __shared__ u16 ldsF[128 * 128];   // F[b]: [o][c] bf16, swizzled rows
    __shared__ u16 ldsX[128 * 128];   // Xt:   [s][c] bf16, swizzled rows

    const int t   = threadIdx.x;
    const int b   = blockIdx.x / nblk;
    const int blk = blockIdx.x % nblk;

    const float* fb = fw + (size_t)b * (128 * 128);
    const float* xb = x  + (size_t)b * 128 * HW;

    // ---- X staging thread map: lane pair -> (c-quad parity, s-quad) ----
    const int sq  = (t >> 1) & 31;              // s-quad 0..31
    const int cqb = (t & 1) + ((t >> 6) << 1);  // c-quad base; +8*it

    f32x4 xv[4][4];   // in-flight X tile, [it][e] (fp32)

    auto issue_x = [&](int st) {
        const float* xt = xb + (size_t)st * 128;
        // clamp keeps the load in-bounds for the level-5 tail (HW=64);
        // garbage lanes are masked at store time and stats are off there.
        const int sg = (st * 128 + sq * 4 < HW) ? sq * 4 : 0;
#pragma unroll
        for (int it = 0; it < 4; ++it) {
            const int cq = cqb + 8 * it;
#pragma unroll
            for (int e = 0; e < 4; ++e)
                xv[it][e] = *reinterpret_cast<const f32x4*>(
                    xt + (size_t)(cq * 4 + e) * HW + sg);
        }
    };

    // prefetch first X tile, then stage F while those loads are in flight
    issue_x(blk);

#pragma unroll
    for (int i = 0; i < 16; ++i) {
        const int fi  = t + 256 * i;            // [128][32] f32x4 granules
        const int row = fi >> 5;                // o
        const int c4  = (fi & 31) * 4;          // c
        f32x4 v = *reinterpret_cast<const f32x4*>(fb + row * 128 + c4);
        *reinterpret_cast<u16x4*>(&ldsF[row * 128 + (c4 ^ swz8(row))]) = cvt4(v);
    }

    const int lane = t & 63;
    const int w    = t >> 6;
    const int wm   = w >> 1;     // wave's M half (o)
    const int wn   = w & 1;      // wave's N half (s)
    const int m16  = lane & 15;
    const int quad = lane >> 4;
    const int q8   = quad * 8;

    const size_t outbase = (size_t)b * 128 * HW;

    for (int st = blk; st < ntiles; st += nblk) {
        // ---- stage X: cvt + 4x4 register transpose -> Xt[s][c] ----
#pragma unroll
        for (int it = 0; it < 4; ++it) {
            const int cq = cqb + 8 * it;
            u16x4 h[4];
#pragma unroll
            for (int e = 0; e < 4; ++e) h[e] = cvt4(xv[it][e]);
#pragma unroll
            for (int e2 = 0; e2 < 4; ++e2) {
                const int s = sq * 4 + e2;
                u16x4 o4 = { h[0][e2], h[1][e2], h[2][e2], h[3][e2] };
                *reinterpret_cast<u16x4*>(
                    &ldsX[s * 128 + ((cq * 4) ^ swz8(s))]) = o4;
            }
        }
        __syncthreads();

        // prefetch next tile's X into registers (overlaps MFMA + epilogue)
        if (st + nblk < ntiles) issue_x(st + nblk);

        // ---- MFMA: all fragments are single ds_read_b128 ----
        f32x4 acc[4][4] = {};
#pragma unroll
        for (int ks = 0; ks < 4; ++ks) {
            const int kb = ks * 32 + q8;
            bf16x8 afr[4], bfr[4];
#pragma unroll
            for (int i = 0; i < 4; ++i) {
                const int r = wm * 64 + i * 16 + m16;    // o row
                afr[i] = *reinterpret_cast<const bf16x8*>(
                    &ldsF[r * 128 + (kb ^ swz8(r))]);
            }
#pragma unroll
            for (int j = 0; j < 4; ++j) {
                const int r = wn * 64 + j * 16 + m16;    // s row (transposed X)
                bfr[j] = *reinterpret_cast<const bf16x8*>(
                    &ldsX[r * 128 + (kb ^ swz8(r))]);
            }
#pragma unroll
            for (int i = 0; i < 4; ++i)
#pragma unroll
                for (int j = 0; j < 4; ++j)
                    acc[i][j] = __builtin_amdgcn_mfma_f32_16x16x32_bf16(
                        afr[i], bfr[j], acc[i][j], 0, 0, 0);
        }

        // ---- epilogue: store y + per-(b,o) stats ----
#pragma unroll
        for (int i = 0; i < 4; ++i) {
#pragma unroll
            for (int r = 0; r < 4; ++r) {
                const int o = wm * 64 + i * 16 + quad * 4 + r;  // C/D row
                float s1 = 0.f, s2 = 0.f;
#pragma unroll
                for (int j = 0; j < 4; ++j) {
                    float v = acc[i][j][r];
                    const int s = st * 128 + wn * 64 + j * 16 + m16;  // C/D col
                    if (s < HW) {
                        const size_t idx = outbase + (size_t)o * HW + s;
                        if constexpr (YBF16)
                            ybf[idx] = __builtin_bit_cast(u16, (bf16)v);
                        else
                            out[idx] = v;
                    }
                    s1 += v; s2 += v * v;
                }
                if (do_stats) {
#pragma unroll
                    for (int off = 8; off; off >>= 1) {
                        s1 += __shfl_xor(s1, off, 64);
                        s2 += __shfl_xor(s2, off, 64);
                    }
                    if (m16 == 0) {
                        atomicAdd(&ysum[b * 128 + o], s1);
                        atomicAdd(&ysq [b * 128 + o], s2);
                    }
                }
            }
        }
        __syncthreads();   // protect ldsX before next tile's staging
    }
}

template<bool INBF16>
__global__ __launch_bounds__(256)
void norm_kernel(const u16* __restrict__ ybf, float* __restrict__ out,
                 const float* __restrict__ ysum, const float* __restrict__ ysq,
                 int log2hw, int n8)
{
    const float invHW = 1.0f / (float)(1 << log2hw);
    const int stride = gridDim.x * blockDim.x;
    for (int i8 = blockIdx.x * blockDim.x + threadIdx.x; i8 < n8; i8 += stride) {
        const int row = i8 >> (log2hw - 3);      // b*128 + o  (HW/8 granules/row)
        const float mean = ysum[row] * invHW;
        const float var  = ysq[row] * invHW - mean * mean;
        const float rstd = rsqrtf(var + 1e-5f);
        f32x4 lo, hi;
        if constexpr (INBF16) {
            u16x8 h = reinterpret_cast<const u16x8*>(ybf)[i8];
            lo = f32x4{ bf2f(h[0]), bf2f(h[1]), bf2f(h[2]), bf2f(h[3]) };
            hi = f32x4{ bf2f(h[4]), bf2f(h[5]), bf2f(h[6]), bf2f(h[7]) };
        } else {
            lo = reinterpret_cast<const f32x4*>(out)[i8 * 2];
            hi = reinterpret_cast<const f32x4*>(out)[i8 * 2 + 1];
        }
#pragma unroll
        for (int k = 0; k < 4; ++k) {
            lo[k] = (lo[k] - mean) * rstd;
            hi[k] = (hi[k] - mean) * rstd;
        }
        reinterpret_cast<f32x4*>(out)[i8 * 2]     = lo;
        reinterpret_cast<f32x4*>(out)[i8 * 2 + 1] = hi;
    }
}

extern "C" void kernel_launch(void* const* d_in, const int* in_sizes, int n_in,
                              void* d_out, int out_size, void* d_ws, size_t ws_size,
                              hipStream_t stream)
{
    (void)in_sizes; (void)n_in; (void)out_size;
    // setup_inputs dict order: x1,l1fs,x2,l2fs,...
    const float* x[5]  = {(const float*)d_in[0], (const float*)d_in[2], (const float*)d_in[4],
                          (const float*)d_in[6], (const float*)d_in[8]};
    const float* fl[5] = {(const float*)d_in[1], (const float*)d_in[3], (const float*)d_in[5],
                          (const float*)d_in[7], (const float*)d_in[9]};
    float* out = (float*)d_out;

    const int HW[5]     = {128 * 128, 64 * 64, 32 * 32, 16 * 16, 8 * 8};
    const int LOG2HW[5] = {14, 12, 10, 8, 6};
    size_t off[5];
    off[0] = 0;
    for (int l = 1; l < 5; ++l) off[l] = off[l - 1] + (size_t)32 * 128 * HW[l - 1];

    float* stats = (float*)d_ws;
    const size_t STATS_BYTES = 4 * 8192 * sizeof(float);   // 4 levels x (4096+4096)

    size_t ybf_off[4];
    size_t need = STATS_BYTES;
    for (int l = 0; l < 4; ++l) { ybf_off[l] = need; need += (size_t)32 * 128 * HW[l] * sizeof(u16); }
    const bool usebf = (ws_size >= need);

    hipMemsetAsync(d_ws, 0, STATS_BYTES, stream);

    for (int l = 0; l < 5; ++l) {
        const int ntiles = (HW[l] + 127) / 128;
        // blocks per sample: amortize F staging over several s-tiles on the
        // big levels while keeping >=512 blocks in flight.
        int nblk = ntiles;
        if (ntiles >= 128)     nblk = 32;   // L1: 4 tiles/block, 1024 blocks
        else if (ntiles >= 32) nblk = 16;   // L2: 2 tiles/block,  512 blocks
        const int grid = 32 * nblk;
        float* ysum = stats + (l < 4 ? l : 0) * 8192;
        float* ysq  = ysum + 4096;
        if (l < 4 && usebf) {
            u16* ybf = (u16*)((char*)d_ws + ybf_off[l]);
            conv_kernel<true><<<grid, 256, 0, stream>>>(x[l], fl[l], out + off[l], ybf,
                                                        ysum, ysq, HW[l], ntiles, nblk, 1);
        } else {
            conv_kernel<false><<<grid, 256, 0, stream>>>(x[l], fl[l], out + off[l], nullptr,
                                                         ysum, ysq, HW[l], ntiles, nblk,
                                                         l < 4 ? 1 : 0);
        }
    }
    for (int l = 0; l < 4; ++l) {
        const int n8 = 32 * 128 * HW[l] / 8;
        int blocks = (n8 + 255) / 256;
        if (blocks > 2048) blocks = 2048;
        float* ysum = stats + l * 8192;
        float* ysq  = ysum + 4096;
        if (usebf) {
            const u16* ybf = (const u16*)((char*)d_ws + ybf_off[l]);
            norm_kernel<true><<<blocks, 256, 0, stream>>>(ybf, out + off[l], ysum, ysq,
                                                          LOG2HW[l], n8);
        } else {
            norm_kernel<false><<<blocks, 256, 0, stream>>>(nullptr, out + off[l], ysum, ysq,
                                                           LOG2HW[l], n8);
        }
    }
}